// Round 2
// baseline (150.622 us; speedup 1.0000x reference)
//
#include <hip/hip_runtime.h>
#include <cmath>

#define LFULL 8192          // signal length
#define NH    4096          // half length = complex FFT size (4^6)
#define BIGI  8192          // sentinel (== n, as in reference)
#define NPAD  (4096 + 128)  // padded LDS leading size (+1 word per 32)

__device__ __forceinline__ int padi(int w){ return w + (w >> 5); }

// 12-bit base-4 digit reversal: bit-reverse 12 bits, then swap bit pairs
__device__ __forceinline__ int drev12(unsigned k){
  unsigned r = __brev(k) >> 20;
  r = ((r & 0x555u) << 1) | ((r >> 1) & 0x555u);
  return (int)r;
}

__device__ __forceinline__ float wmaxf(float v){
#pragma unroll
  for (int o = 32; o; o >>= 1) v = fmaxf(v, __shfl_xor(v, o));
  return v;
}
__device__ __forceinline__ float wminf(float v){
#pragma unroll
  for (int o = 32; o; o >>= 1) v = fminf(v, __shfl_xor(v, o));
  return v;
}
__device__ __forceinline__ double wsumd(double v){
#pragma unroll
  for (int o = 32; o; o >>= 1) v += __shfl_xor(v, o);
  return v;
}
__device__ __forceinline__ int wsumi(int v){
#pragma unroll
  for (int o = 32; o; o >>= 1) v += __shfl_xor(v, o);
  return v;
}
__device__ __forceinline__ int wmini(int v){
#pragma unroll
  for (int o = 32; o; o >>= 1) v = min(v, __shfl_xor(v, o));
  return v;
}
__device__ __forceinline__ int wmaxi(int v){
#pragma unroll
  for (int o = 32; o; o >>= 1) v = max(v, __shfl_xor(v, o));
  return v;
}

// packed signal accessor: x[i] = (i even) ? re[i/2] : im[i/2]
#define XS(i) lds[(i) & 1][padi((i) >> 1)]

__global__ __launch_bounds__(256)
void feat_kernel(const float* __restrict__ x, float* __restrict__ out, int nrows){
  const int b = blockIdx.x;
  const float* __restrict__ row = x + (size_t)b * LFULL;

  __shared__ float  lds[2][NPAD];   // [0]=re (even samples), [1]=im (odd samples)
  __shared__ double sd[4][3];
  __shared__ float  sf[4][2];
  __shared__ int    si[4][6];
  __shared__ int    sb_i[4];        // P0, V0, V1, VL (post-valid)
  __shared__ float  sb_hh;

  const int t    = threadIdx.x;
  const int lane = t & 63;
  const int wid  = t >> 6;

  // ---------------- load + pack (coalesced float4) ----------------
  const float4* __restrict__ row4 = (const float4*)row;
#pragma unroll
  for (int it = 0; it < 8; ++it){
    int j = t + (it << 8);              // 0..2047
    float4 f = row4[j];
    lds[0][padi(2*j    )] = f.x;
    lds[1][padi(2*j    )] = f.y;
    lds[0][padi(2*j + 1)] = f.z;
    lds[1][padi(2*j + 1)] = f.w;
  }
  __syncthreads();

  // ---------------- Phase A: stats + peak/valley indices ----------------
  float  mx = -INFINITY, mn = INFINITY;
  double sum = 0.0, sumsq = 0.0;
  int npk = 0, nvl = 0, p0 = BIGI, va = BIGI, vb = BIGI, vl = -1;
#pragma unroll 4
  for (int c = 0; c < 32; ++c){
    int i = t + (c << 8);               // strided -> conflict-free LDS
    float x0 = XS(i);
    mx = fmaxf(mx, x0); mn = fminf(mn, x0);
    sum += (double)x0; sumsq += (double)x0 * (double)x0;
    if (i >= 1 && i <= LFULL - 2){
      float xm = XS(i - 1), xp = XS(i + 1);
      bool pk = (x0 > xm) && (x0 > xp);
      bool vv = (x0 < xm) && (x0 < xp);
      npk += pk; nvl += vv;
      if (pk && p0 == BIGI) p0 = i;     // i increasing per-thread
      if (vv){ if (va == BIGI) va = i; else if (vb == BIGI) vb = i; vl = i; }
    }
  }
  mx = wmaxf(mx); mn = wminf(mn);
  sum = wsumd(sum); sumsq = wsumd(sumsq);
  npk = wsumi(npk); nvl = wsumi(nvl);
  p0 = wmini(p0); vl = wmaxi(vl);
#pragma unroll
  for (int o = 32; o; o >>= 1){         // two-smallest valley indices
    int oa = __shfl_xor(va, o), ob = __shfl_xor(vb, o);
    int na = min(va, oa);
    int nb = min(max(va, oa), min(vb, ob));
    va = na; vb = nb;
  }
  if (lane == 0){
    sf[wid][0] = mx;  sf[wid][1] = mn;
    sd[wid][0] = sum; sd[wid][1] = sumsq;
    si[wid][0] = npk; si[wid][1] = nvl; si[wid][2] = p0;
    si[wid][3] = va;  si[wid][4] = vb;  si[wid][5] = vl;
  }
  __syncthreads();

  int   t0_valid = 0;
  float t0_ph = 0.f;
  double t0_sum = 0.0, t0_sumsq = 0.0;
  float t0_mx = 0.f, t0_mn = 0.f;
  if (t == 0){
    mx = sf[0][0]; mn = sf[0][1]; sum = sd[0][0]; sumsq = sd[0][1];
    npk = si[0][0]; nvl = si[0][1]; p0 = si[0][2];
    va = si[0][3]; vb = si[0][4]; vl = si[0][5];
    for (int w = 1; w < 4; ++w){
      mx = fmaxf(mx, sf[w][0]); mn = fminf(mn, sf[w][1]);
      sum += sd[w][0]; sumsq += sd[w][1];
      npk += si[w][0]; nvl += si[w][1];
      p0 = min(p0, si[w][2]);
      int oa = si[w][3], ob = si[w][4];
      int na = min(va, oa);
      int nb = min(max(va, oa), min(vb, ob));
      va = na; vb = nb;
      vl = max(vl, si[w][5]);
    }
    t0_valid = (npk >= 1) && (nvl >= 2);
    int P0 = t0_valid ? p0 : 0, V0 = t0_valid ? va : 0;
    int V1 = t0_valid ? vb : 0, VL = t0_valid ? vl : 0;
    sb_i[0] = P0; sb_i[1] = V0; sb_i[2] = V1; sb_i[3] = VL;
    float xp0 = XS(P0), xv0 = XS(V0);
    sb_hh = 0.5f * (xp0 + xv0);
    t0_ph = xp0 - xv0;
    t0_sum = sum; t0_sumsq = sumsq; t0_mx = mx; t0_mn = mn;
  }
  __syncthreads();
  const int   P0 = sb_i[0], V0 = sb_i[1], V1 = sb_i[2], VL = sb_i[3];
  const float hh = sb_hh;

  // ---------------- Phase B: trapz windows + half-height width ----------------
  double pa = 0.0, a2 = 0.0, a1 = 0.0;
  int li = BIGI, ri = -1;
#pragma unroll 4
  for (int c = 0; c < 32; ++c){
    int i = t + (c << 8);
    if (i < LFULL - 1){
      float x0 = XS(i), x1 = XS(i + 1);
      float seg = (x0 + x1) * (0.5f / 30.0f);
      if (i >= V0 && i + 2 <= VL) pa += (double)seg;
      if (i >= P0 && i + 2 <= V1) a2 += (double)seg;
      if (i >= V0 && i + 2 <= P0) a1 += (double)seg;
      if (x0 >= hh){
        if (i >= V0 && i <  P0 && i < li) li = i;
        if (i >  V0 && i <= P0 && i > ri) ri = i;
      }
    }
  }
  pa = wsumd(pa); a2 = wsumd(a2); a1 = wsumd(a1);
  li = wmini(li); ri = wmaxi(ri);
  if (lane == 0){
    sd[wid][0] = pa; sd[wid][1] = a2; sd[wid][2] = a1;
    si[wid][0] = li; si[wid][1] = ri;
  }
  __syncthreads();   // also guards lds reads before FFT overwrites

  float F0=0,F1=0,F2=0,F3=0,F5=0,F6=0,F7=0,F8=0,F9=0;
  if (t == 0){
    pa = sd[0][0]; a2 = sd[0][1]; a1 = sd[0][2]; li = si[0][0]; ri = si[0][1];
    for (int w = 1; w < 4; ++w){
      pa += sd[w][0]; a2 += sd[w][1]; a1 += sd[w][2];
      li = min(li, si[w][0]); ri = max(ri, si[w][1]);
    }
    double n = (double)LFULL;
    double var = (t0_sumsq - t0_sum * t0_sum / n) / (n - 1.0);
    F0 = t0_mx; F1 = t0_mx - t0_mn; F2 = (float)var; F3 = (float)sqrt(var);
    if (t0_valid){
      int LI = (li == BIGI) ? V0 : li;
      int RI = (ri == -1)   ? P0 : ri;
      F5 = (float)pa; F6 = (float)a2; F7 = t0_ph; F8 = (float)a1;
      F9 = (float)(RI - LI) / 30.0f;
    }
  }

  // ---------------- Phase C: radix-4 DIF FFT (N=4096), in-place, no reorder --------
#pragma unroll 1
  for (int s = 0; s < 6; ++s){
    const int lm = 12 - 2 * s;          // log2(m): m = 4096,1024,256,64,16,4
    const int q  = 1 << (lm - 2);
    const float cstep = -6.2831853071795864f / (float)(1 << lm);
#pragma unroll
    for (int k = 0; k < 4; ++k){
      int bf  = t + (k << 8);           // 0..1023
      int j   = bf & (q - 1);
      int blk = bf >> (lm - 2);
      int i0  = (blk << lm) + j;
      int pi0 = padi(i0), pi1 = padi(i0 + q), pi2 = padi(i0 + 2*q), pi3 = padi(i0 + 3*q);
      float ar = lds[0][pi0], ai = lds[1][pi0];
      float br = lds[0][pi1], bi = lds[1][pi1];
      float cr = lds[0][pi2], ci = lds[1][pi2];
      float dr = lds[0][pi3], di = lds[1][pi3];
      float t0r = ar + cr, t0i = ai + ci;
      float t1r = ar - cr, t1i = ai - ci;
      float t2r = br + dr, t2i = bi + di;
      float t3r = br - dr, t3i = bi - di;
      float u0r = t0r + t2r, u0i = t0i + t2i;
      float u2r = t0r - t2r, u2i = t0i - t2i;
      float u1r = t1r + t3i, u1i = t1i - t3r;   // t1 - i*t3
      float u3r = t1r - t3i, u3i = t1i + t3r;   // t1 + i*t3
      float s1, c1; __sincosf(cstep * (float)j, &s1, &c1);
      float c2 = c1*c1 - s1*s1, s2 = 2.f*c1*s1;
      float c3 = c1*c2 - s1*s2, s3 = c1*s2 + s1*c2;
      lds[0][pi0] = u0r;               lds[1][pi0] = u0i;
      lds[0][pi1] = u1r*c1 - u1i*s1;   lds[1][pi1] = u1r*s1 + u1i*c1;
      lds[0][pi2] = u2r*c2 - u2i*s2;   lds[1][pi2] = u2r*s2 + u2i*c2;
      lds[0][pi3] = u3r*c3 - u3i*s3;   lds[1][pi3] = u3r*s3 + u3i*c3;
    }
    __syncthreads();
  }

  // ---------------- Hermitian unpack + |X| sum (digit-reversed positions) ------
  double magsum = 0.0;
#pragma unroll 4
  for (int c = 0; c < 16; ++c){
    int k  = t + (c << 8);                       // 0..4095
    int kk = (NH - k) & (NH - 1);
    int pz = padi(drev12((unsigned)k));
    int pn = padi(drev12((unsigned)kk));
    float zr = lds[0][pz], zi = lds[1][pz];      // Z[k]
    float wr = lds[0][pn], wi = lds[1][pn];      // Z[N-k]
    float er  = 0.5f * (zr + wr), ei = 0.5f * (zi - wi);   // E[k]
    float orr = 0.5f * (zi + wi), oi = 0.5f * (wr - zr);   // O[k]
    float sw, cw; __sincosf((-6.2831853071795864f / 8192.f) * (float)k, &sw, &cw);
    float tr = orr*cw - oi*sw, ti = orr*sw + oi*cw;
    float x1r = er + tr, x1i = ei + ti;          // X[k]
    float x2r = er - tr, x2i = ei - ti;          // X[k+4096]
    magsum += (double)sqrtf(x1r*x1r + x1i*x1i);
    magsum += (double)sqrtf(x2r*x2r + x2i*x2i);
  }
  magsum = wsumd(magsum);
  if (lane == 0) sd[wid][0] = magsum;
  __syncthreads();

  if (t == 0){
    double ms = sd[0][0] + sd[1][0] + sd[2][0] + sd[3][0];
    float F4 = (float)(ms / (double)LFULL);
    float* __restrict__ o = out + (size_t)b * 10;
    o[0]=F0; o[1]=F1; o[2]=F2; o[3]=F3; o[4]=F4;
    o[5]=F5; o[6]=F6; o[7]=F7; o[8]=F8; o[9]=F9;
  }
}

extern "C" void kernel_launch(void* const* d_in, const int* in_sizes, int n_in,
                              void* d_out, int out_size, void* d_ws, size_t ws_size,
                              hipStream_t stream){
  const float* x = (const float*)d_in[0];
  float* out = (float*)d_out;
  int nrows = in_sizes[0] / LFULL;
  hipLaunchKernelGGL(feat_kernel, dim3(nrows), dim3(256), 0, stream, x, out, nrows);
}

// Round 3
// 122.282 us; speedup vs baseline: 1.2318x; 1.2318x over previous
//
#include <hip/hip_runtime.h>
#include <cmath>

#define LFULL 8192
#define NH    4096
#define BIGI  8192
#define NPAD  (4096 + 128)   // +1 word per 32 padding

__device__ __forceinline__ int padi(int w){ return w + (w >> 5); }

// base-4 digit reversal of 6 digits (12 bits)
__device__ __forceinline__ int drev12(unsigned k){
  unsigned r = __brev(k) >> 20;
  r = ((r & 0x555u) << 1) | ((r >> 1) & 0x555u);
  return (int)r;
}

__device__ __forceinline__ float wmaxf(float v){
#pragma unroll
  for (int o = 32; o; o >>= 1) v = fmaxf(v, __shfl_xor(v, o));
  return v;
}
__device__ __forceinline__ float wminf(float v){
#pragma unroll
  for (int o = 32; o; o >>= 1) v = fminf(v, __shfl_xor(v, o));
  return v;
}
__device__ __forceinline__ float wsumf(float v){
#pragma unroll
  for (int o = 32; o; o >>= 1) v += __shfl_xor(v, o);
  return v;
}
__device__ __forceinline__ int wsumi(int v){
#pragma unroll
  for (int o = 32; o; o >>= 1) v += __shfl_xor(v, o);
  return v;
}
__device__ __forceinline__ int wmini(int v){
#pragma unroll
  for (int o = 32; o; o >>= 1) v = min(v, __shfl_xor(v, o));
  return v;
}
__device__ __forceinline__ int wmaxi(int v){
#pragma unroll
  for (int o = 32; o; o >>= 1) v = max(v, __shfl_xor(v, o));
  return v;
}

// 16-point DFT = two radix-4 DIF stages in registers.
// Input: v[d] holds data at global position base + stride*d.
// Stage A twiddle for butterfly d, leg r:  w^r * W16^{d*r}
// Stage B twiddle (uniform):               (w^4)^r
// w = W4096^t (phase0), W256^(t&15) (phase1), 1 (phase2).
__device__ __forceinline__ void dft16(float* vr, float* vi, float wr, float wi){
  // W16^k table, k in {0,1,2,3,4,6,9} (others unused)
  const float OR[10] = {1.f, 0.9238795325112867f, 0.7071067811865476f, 0.3826834323650898f,
                        0.f, 0.f, -0.7071067811865476f, 0.f, 0.f, -0.9238795325112867f};
  const float OI[10] = {0.f,-0.3826834323650898f,-0.7071067811865476f,-0.9238795325112867f,
                       -1.f, 0.f, -0.7071067811865476f, 0.f, 0.f, 0.3826834323650898f};
  const float w2r = wr*wr - wi*wi,  w2i = 2.f*wr*wi;
  const float w3r = w2r*wr - w2i*wi, w3i = w2r*wi + w2i*wr;
  const float prt[4] = {1.f, wr, w2r, w3r};
  const float pit[4] = {0.f, wi, w2i, w3i};
  // ---- stage A: legs (d, d+4, d+8, d+12) ----
#pragma unroll
  for (int d = 0; d < 4; ++d){
    float t0r = vr[d]    + vr[d+8],  t0i = vi[d]    + vi[d+8];
    float t1r = vr[d]    - vr[d+8],  t1i = vi[d]    - vi[d+8];
    float t2r = vr[d+4]  + vr[d+12], t2i = vi[d+4]  + vi[d+12];
    float t3r = vr[d+4]  - vr[d+12], t3i = vi[d+4]  - vi[d+12];
    float u0r = t0r + t2r, u0i = t0i + t2i;
    float u2r = t0r - t2r, u2i = t0i - t2i;
    float u1r = t1r + t3i, u1i = t1i - t3r;   // t1 - i*t3
    float u3r = t1r - t3i, u3i = t1i + t3r;   // t1 + i*t3
    float T1r = prt[1]*OR[d]   - pit[1]*OI[d];
    float T1i = prt[1]*OI[d]   + pit[1]*OR[d];
    float T2r = prt[2]*OR[2*d] - pit[2]*OI[2*d];
    float T2i = prt[2]*OI[2*d] + pit[2]*OR[2*d];
    float T3r = prt[3]*OR[3*d] - pit[3]*OI[3*d];
    float T3i = prt[3]*OI[3*d] + pit[3]*OR[3*d];
    vr[d]    = u0r;                 vi[d]    = u0i;
    vr[d+4]  = u1r*T1r - u1i*T1i;   vi[d+4]  = u1r*T1i + u1i*T1r;
    vr[d+8]  = u2r*T2r - u2i*T2i;   vi[d+8]  = u2r*T2i + u2i*T2r;
    vr[d+12] = u3r*T3r - u3i*T3i;   vi[d+12] = u3r*T3i + u3i*T3r;
  }
  // ---- stage B: legs (4g, 4g+1, 4g+2, 4g+3) ----
  const float U1r = w2r*w2r - w2i*w2i, U1i = 2.f*w2r*w2i;        // w^4
  const float U2r = U1r*U1r - U1i*U1i, U2i = 2.f*U1r*U1i;        // w^8
  const float U3r = U2r*U1r - U2i*U1i, U3i = U2r*U1i + U2i*U1r;  // w^12
#pragma unroll
  for (int g = 0; g < 4; ++g){
    const int i0 = 4*g;
    float t0r = vr[i0]   + vr[i0+2], t0i = vi[i0]   + vi[i0+2];
    float t1r = vr[i0]   - vr[i0+2], t1i = vi[i0]   - vi[i0+2];
    float t2r = vr[i0+1] + vr[i0+3], t2i = vi[i0+1] + vi[i0+3];
    float t3r = vr[i0+1] - vr[i0+3], t3i = vi[i0+1] - vi[i0+3];
    float u0r = t0r + t2r, u0i = t0i + t2i;
    float u2r = t0r - t2r, u2i = t0i - t2i;
    float u1r = t1r + t3i, u1i = t1i - t3r;
    float u3r = t1r - t3i, u3i = t1i + t3r;
    vr[i0]   = u0r;                 vi[i0]   = u0i;
    vr[i0+1] = u1r*U1r - u1i*U1i;   vi[i0+1] = u1r*U1i + u1i*U1r;
    vr[i0+2] = u2r*U2r - u2i*U2i;   vi[i0+2] = u2r*U2i + u2i*U2r;
    vr[i0+3] = u3r*U3r - u3i*U3i;   vi[i0+3] = u3r*U3i + u3i*U3r;
  }
}

__global__ __launch_bounds__(256)
void feat_kernel(const float* __restrict__ x, float* __restrict__ out){
  const int b = blockIdx.x;
  const float* __restrict__ row = x + (size_t)b * LFULL;

  __shared__ float re[NPAD], im[NPAD];      // packed: re=even samples, im=odd
  __shared__ float sfirst[256], slast[256];
  __shared__ float sdA[4][4];
  __shared__ float sfA[4][2];
  __shared__ int   siA[4][6];
  __shared__ int   sb_i[4];                 // P0, V0, V1, VL
  __shared__ float sb_hh;

  const int t    = threadIdx.x;
  const int lane = t & 63;
  const int wid  = t >> 6;

  // ---------- load 32 contiguous samples into registers ----------
  float v[32];
  const float4* __restrict__ rp = (const float4*)(row + (t << 5));
#pragma unroll
  for (int q = 0; q < 8; ++q){
    float4 f = rp[q];
    v[4*q] = f.x; v[4*q+1] = f.y; v[4*q+2] = f.z; v[4*q+3] = f.w;
  }
  // pack into LDS for the FFT + boundary exchange
#pragma unroll
  for (int c = 0; c < 16; ++c){
    int j = (t << 4) + c;
    re[padi(j)] = v[2*c];
    im[padi(j)] = v[2*c+1];
  }
  sfirst[t] = v[0]; slast[t] = v[31];
  __syncthreads();                          // S1

  const float xm_prev = (t > 0)   ? slast[t-1]  : 0.f;
  const float xp_next = (t < 255) ? sfirst[t+1] : 0.f;

  // ---------- Phase A: stats + peak/valley (registers only) ----------
  float mx = -INFINITY, mn = INFINITY, sum = 0.f, sumsq = 0.f;
  int npk = 0, nvl = 0, p0 = BIGI, va = BIGI, vb = BIGI, vl = -1;
#pragma unroll
  for (int c = 0; c < 32; ++c){
    const int i = (t << 5) + c;
    const float x0 = v[c];
    mx = fmaxf(mx, x0); mn = fminf(mn, x0);
    sum += x0; sumsq = fmaf(x0, x0, sumsq);
    const float xm = (c == 0)  ? xm_prev : v[(c == 0)  ? 0  : c-1];
    const float xp = (c == 31) ? xp_next : v[(c == 31) ? 31 : c+1];
    if (i >= 1 && i <= LFULL - 2){
      bool pk = (x0 > xm) && (x0 > xp);
      bool vv = (x0 < xm) && (x0 < xp);
      npk += pk; nvl += vv;
      if (pk && p0 == BIGI) p0 = i;
      if (vv){ if (va == BIGI) va = i; else if (vb == BIGI) vb = i; vl = i; }
    }
  }
  mx = wmaxf(mx); mn = wminf(mn);
  sum = wsumf(sum); sumsq = wsumf(sumsq);
  npk = wsumi(npk); nvl = wsumi(nvl);
  p0 = wmini(p0); vl = wmaxi(vl);
#pragma unroll
  for (int o = 32; o; o >>= 1){             // two-smallest valley indices
    int oa = __shfl_xor(va, o), ob = __shfl_xor(vb, o);
    int na = min(va, oa);
    int nb = min(max(va, oa), min(vb, ob));
    va = na; vb = nb;
  }
  if (lane == 0){
    sfA[wid][0] = mx;  sfA[wid][1] = mn;
    sdA[wid][0] = sum; sdA[wid][1] = sumsq;
    siA[wid][0] = npk; siA[wid][1] = nvl; siA[wid][2] = p0;
    siA[wid][3] = va;  siA[wid][4] = vb;  siA[wid][5] = vl;
  }
  __syncthreads();                          // S2

  int    t0_valid = 0;
  float  t0_ph = 0.f, t0_mx = 0.f, t0_mn = 0.f;
  double t0_sum = 0.0, t0_sumsq = 0.0;
  if (t == 0){
    mx = sfA[0][0]; mn = sfA[0][1];
    double dsum = sdA[0][0], dss = sdA[0][1];
    npk = siA[0][0]; nvl = siA[0][1]; p0 = siA[0][2];
    va = siA[0][3]; vb = siA[0][4]; vl = siA[0][5];
    for (int w = 1; w < 4; ++w){
      mx = fmaxf(mx, sfA[w][0]); mn = fminf(mn, sfA[w][1]);
      dsum += sdA[w][0]; dss += sdA[w][1];
      npk += siA[w][0]; nvl += siA[w][1];
      p0 = min(p0, siA[w][2]);
      int oa = siA[w][3], ob = siA[w][4];
      int na = min(va, oa);
      int nb = min(max(va, oa), min(vb, ob));
      va = na; vb = nb;
      vl = max(vl, siA[w][5]);
    }
    t0_valid = (npk >= 1) && (nvl >= 2);
    int P0 = t0_valid ? p0 : 0, V0 = t0_valid ? va : 0;
    int V1 = t0_valid ? vb : 0, VL = t0_valid ? vl : 0;
    sb_i[0] = P0; sb_i[1] = V0; sb_i[2] = V1; sb_i[3] = VL;
    float xp0 = (P0 & 1) ? im[padi(P0 >> 1)] : re[padi(P0 >> 1)];
    float xv0 = (V0 & 1) ? im[padi(V0 >> 1)] : re[padi(V0 >> 1)];
    sb_hh = 0.5f * (xp0 + xv0);
    t0_ph = xp0 - xv0;
    t0_sum = dsum; t0_sumsq = dss; t0_mx = mx; t0_mn = mn;
  }
  __syncthreads();                          // S3
  const int   P0 = sb_i[0], V0 = sb_i[1], V1 = sb_i[2], VL = sb_i[3];
  const float hh = sb_hh;

  // ---------- Phase B: trapz windows + half-height (registers only) ----------
  float pa = 0.f, a2 = 0.f, a1 = 0.f;
  int li = BIGI, ri = -1;
#pragma unroll
  for (int c = 0; c < 32; ++c){
    const int i = (t << 5) + c;
    if (i < LFULL - 1){
      const float x0 = v[c];
      const float x1 = (c == 31) ? xp_next : v[(c == 31) ? 31 : c+1];
      const float seg = (x0 + x1) * (0.5f / 30.0f);
      if (i >= V0 && i + 2 <= VL) pa += seg;
      if (i >= P0 && i + 2 <= V1) a2 += seg;
      if (i >= V0 && i + 2 <= P0) a1 += seg;
      if (x0 >= hh){
        if (i >= V0 && i <  P0 && i < li) li = i;
        if (i >  V0 && i <= P0 && i > ri) ri = i;
      }
    }
  }
  pa = wsumf(pa); a2 = wsumf(a2); a1 = wsumf(a1);
  li = wmini(li); ri = wmaxi(ri);
  if (lane == 0){
    sdA[wid][0] = pa; sdA[wid][1] = a2; sdA[wid][2] = a1;
    siA[wid][0] = li; siA[wid][1] = ri;
  }
  // no sync needed here: FFT below touches only re/im; t0 reads sdA/siA after later syncs

  // ---------- FFT: 3 register-blocked radix-16 phases ----------
  float ar[16], ai[16];

  // phase 0: indices t + 256*d ; w = W4096^t
#pragma unroll
  for (int d = 0; d < 16; ++d){
    int p = padi(t + (d << 8));
    ar[d] = re[p]; ai[d] = im[p];
  }
  {
    float swr, swi;
    __sincosf(-1.5339807878856412e-3f * (float)t, &swi, &swr);
    dft16(ar, ai, swr, swi);
  }
#pragma unroll
  for (int d = 0; d < 16; ++d){
    int p = padi(t + (d << 8));
    re[p] = ar[d]; im[p] = ai[d];
  }
  __syncthreads();                          // S4

  // phase 1: indices (t>>4)*256 + (t&15) + 16*d ; w = W256^(t&15)
  {
    const int hi = t >> 4, lo = t & 15;
#pragma unroll
    for (int d = 0; d < 16; ++d){
      int p = padi((hi << 8) + lo + (d << 4));
      ar[d] = re[p]; ai[d] = im[p];
    }
    float swr, swi;
    __sincosf(-2.4543692606170259e-2f * (float)lo, &swi, &swr);
    dft16(ar, ai, swr, swi);
#pragma unroll
    for (int d = 0; d < 16; ++d){
      int p = padi((hi << 8) + lo + (d << 4));
      re[p] = ar[d]; im[p] = ai[d];
    }
  }
  __syncthreads();                          // S5

  // phase 2: indices 16*t + d ; w = 1 ; write to digit-reversed positions
#pragma unroll
  for (int d = 0; d < 16; ++d){
    int p = padi((t << 4) + d);
    ar[d] = re[p]; ai[d] = im[p];
  }
  __syncthreads();                          // S6 (all reads before scattered writes)
  dft16(ar, ai, 1.f, 0.f);
#pragma unroll
  for (int d = 0; d < 16; ++d){
    int p = padi(drev12((unsigned)((t << 4) + d)));
    re[p] = ar[d]; im[p] = ai[d];
  }
  __syncthreads();                          // S7  -> natural order: Z[k] at k

  // ---------- Hermitian unpack + |X| sum ----------
  float msum = 0.f;
  {
    float cwr, cwi;
    __sincosf(-7.6699039394282058e-4f * (float)t, &cwi, &cwr);  // W8192^t
    const float WSr = 0.9807852804032304f, WSi = -0.1950903220161283f; // W8192^256 = W32
#pragma unroll
    for (int c = 0; c < 16; ++c){
      int k  = t + (c << 8);
      int kk = (NH - k) & (NH - 1);
      float zr = re[padi(k)],  zi = im[padi(k)];
      float yr = re[padi(kk)], yi = im[padi(kk)];
      float er  = 0.5f * (zr + yr), ei = 0.5f * (zi - yi);
      float orr = 0.5f * (zi + yi), oi = 0.5f * (yr - zr);
      float tr = orr*cwr - oi*cwi, ti = orr*cwi + oi*cwr;
      float x1r = er + tr, x1i = ei + ti;
      float x2r = er - tr, x2i = ei - ti;
      msum += sqrtf(x1r*x1r + x1i*x1i);
      msum += sqrtf(x2r*x2r + x2i*x2i);
      float ncr = cwr*WSr - cwi*WSi;        // advance twiddle by W32
      cwi = cwr*WSi + cwi*WSr; cwr = ncr;
    }
  }
  msum = wsumf(msum);
  if (lane == 0) sdA[wid][3] = msum;
  __syncthreads();                          // S8

  if (t == 0){
    float paT = sdA[0][0] + sdA[1][0] + sdA[2][0] + sdA[3][0];
    float a2T = sdA[0][1] + sdA[1][1] + sdA[2][1] + sdA[3][1];
    float a1T = sdA[0][2] + sdA[1][2] + sdA[2][2] + sdA[3][2];
    float msT = sdA[0][3] + sdA[1][3] + sdA[2][3] + sdA[3][3];
    int liT = min(min(siA[0][0], siA[1][0]), min(siA[2][0], siA[3][0]));
    int riT = max(max(siA[0][1], siA[1][1]), max(siA[2][1], siA[3][1]));
    double n = (double)LFULL;
    double var = (t0_sumsq - t0_sum * t0_sum / n) / (n - 1.0);
    float F0 = t0_mx, F1 = t0_mx - t0_mn, F2 = (float)var, F3 = (float)sqrt(var);
    float F4 = msT / (float)LFULL;
    float F5 = 0.f, F6 = 0.f, F7 = 0.f, F8 = 0.f, F9 = 0.f;
    if (t0_valid){
      int LI = (liT == BIGI) ? V0 : liT;
      int RI = (riT == -1)   ? P0 : riT;
      F5 = paT; F6 = a2T; F7 = t0_ph; F8 = a1T;
      F9 = (float)(RI - LI) / 30.0f;
    }
    float* __restrict__ o = out + (size_t)b * 10;
    o[0]=F0; o[1]=F1; o[2]=F2; o[3]=F3; o[4]=F4;
    o[5]=F5; o[6]=F6; o[7]=F7; o[8]=F8; o[9]=F9;
  }
}

extern "C" void kernel_launch(void* const* d_in, const int* in_sizes, int n_in,
                              void* d_out, int out_size, void* d_ws, size_t ws_size,
                              hipStream_t stream){
  const float* x = (const float*)d_in[0];
  float* out = (float*)d_out;
  int nrows = in_sizes[0] / LFULL;
  hipLaunchKernelGGL(feat_kernel, dim3(nrows), dim3(256), 0, stream, x, out);
}